// Round 3
// baseline (286.339 us; speedup 1.0000x reference)
//
#include <hip/hip_runtime.h>

#define MDIM 8192
#define NDIM 8192
#define KDIM 64

typedef __attribute__((ext_vector_type(8))) short bf16x8;
typedef __attribute__((ext_vector_type(4))) float f32x4;

__device__ __forceinline__ unsigned short f32_to_bf16(float f) {
    union { float f; unsigned int u; } v;
    v.f = f;
    unsigned int u = v.u;
    u += 0x7FFFu + ((u >> 16) & 1u);  // round-to-nearest-even
    return (unsigned short)(u >> 16);
}

// ---------------------------------------------------------------------------
// Prep kernel (unchanged layout): convert A and B^T to bf16, tiled +
// XOR-swizzled, into ws.
//   wsA = ws[0 .. 64*8192)        : 64 m-tiles, tile t = A[t*128..+127][0..63]
//   wsB = ws[64*8192 .. 128*8192) : 64 n-tiles, tile t = B^T[t*128..+127][0..63]
// Within a tile (ushort units): elem (r, k) at  r*64 + ((k>>3)^(r&7))*8 + (k&7)
// ---------------------------------------------------------------------------
__global__ __launch_bounds__(256, 8)
void prep_kernel(const float* __restrict__ A, const float* __restrict__ B,
                 unsigned short* __restrict__ ws) {
    const int tid = threadIdx.x;
    const int bid = blockIdx.x;
    if (bid < 64) {
        const int m0 = bid << 7;
        const int row_base = tid >> 4;       // 0..15
        const int col = (tid & 15) << 2;     // 0,4,...,60
#pragma unroll
        for (int i = 0; i < 8; ++i) {
            const int row = row_base + (i << 4);
            const float4 v =
                *reinterpret_cast<const float4*>(&A[(size_t)(m0 + row) * KDIM + col]);
            ushort4 h;
            h.x = f32_to_bf16(v.x);
            h.y = f32_to_bf16(v.y);
            h.z = f32_to_bf16(v.z);
            h.w = f32_to_bf16(v.w);
            const size_t off = ((size_t)bid << 13) + row * 64 +
                               (((col >> 3) ^ (row & 7)) << 3) + (col & 7);
            *reinterpret_cast<ushort4*>(&ws[off]) = h;
        }
    } else {
        const int bt = bid - 64;
        const int n0 = bt << 7;
#pragma unroll
        for (int i = 0; i < 8; ++i) {
            const int n = (tid & 63) + ((i & 1) << 6);            // 0..127
            const int k0 = ((tid >> 6) << 2) + ((i >> 1) << 4);   // 0,4,...,60
            const size_t gb = (size_t)k0 * NDIM + n0 + n;
            ushort4 h;
            h.x = f32_to_bf16(B[gb]);
            h.y = f32_to_bf16(B[gb + NDIM]);
            h.z = f32_to_bf16(B[gb + 2 * NDIM]);
            h.w = f32_to_bf16(B[gb + 3 * NDIM]);
            const size_t off = ((size_t)(64 + bt) << 13) + n * 64 +
                               (((k0 >> 3) ^ (n & 7)) << 3) + (k0 & 7);
            *reinterpret_cast<ushort4*>(&ws[off]) = h;
        }
    }
}

// ---------------------------------------------------------------------------
// Main kernel: row-streaming blocks. Block bid owns C rows [bid*16, bid*16+16)
// across ALL 8192 columns -> each row is written as one sequential 32 KB
// stream (page-sequential, fill-kernel-like). A/B fragments are read directly
// from the L2-resident pre-swizzled ws (no input LDS staging). Per 1024-col
// chunk: compute 16x1024 -> XOR-swizzled 64 KB LDS bounce -> each wave streams
// 4 full rows in plain 1 KB global_store_dwordx4.
// ---------------------------------------------------------------------------
__global__ __launch_bounds__(256, 2)
void tmatmul_kernel(const unsigned short* __restrict__ ws, float* __restrict__ C) {
    __shared__ __align__(16) float bounce[16 * 1024];  // 64 KB

    const int tid = threadIdx.x;
    const int lane = tid & 63;
    const int wv = tid >> 6;
    const int l15 = lane & 15;
    const int quad = lane >> 4;
    const int x = l15 & 7;          // row-dependent XOR key (granule swizzle)
    const int bid = blockIdx.x;     // 0..511 -> rows bid*16 .. +15

    const unsigned short* wsA = ws;
    const unsigned short* wsB = ws + ((size_t)64 << 13);

    // ---- A fragments: row (bid*16 + l15), both k-steps. 2 x 16B loads. ----
    bf16x8 afrag[2];
    {
        const int ta = bid >> 3;                  // 128-row A tile
        const int ra = ((bid & 7) << 4) + l15;    // row within tile; ra&7 == x
        const unsigned short* pa = wsA + ((size_t)ta << 13) + (size_t)ra * 64;
#pragma unroll
        for (int ks = 0; ks < 2; ++ks)
            afrag[ks] = *reinterpret_cast<const bf16x8*>(
                pa + (((ks * 4 + quad) ^ x) << 3));
    }

    const int colw = wv << 8;  // wave's 256-col slice within each 1024 chunk
    const f32x4 zero = {0.0f, 0.0f, 0.0f, 0.0f};

    for (int ch = 0; ch < 8; ++ch) {
        // ---- Compute 16 rows x 256 cols (this wave's slice). No LDS use. ----
        f32x4 acc[16];
#pragma unroll
        for (int nt = 0; nt < 16; ++nt) acc[nt] = zero;

#pragma unroll
        for (int nt = 0; nt < 16; ++nt) {
            const int n = (ch << 10) + colw + (nt << 4) + l15;  // n&7 == x
            const unsigned short* pb =
                wsB + ((size_t)(n >> 7) << 13) + (size_t)(n & 127) * 64;
            const bf16x8 b0 =
                *reinterpret_cast<const bf16x8*>(pb + ((quad ^ x) << 3));
            const bf16x8 b1 =
                *reinterpret_cast<const bf16x8*>(pb + (((4 + quad) ^ x) << 3));
            acc[nt] = __builtin_amdgcn_mfma_f32_16x16x32_bf16(b0, afrag[0],
                                                              acc[nt], 0, 0, 0);
            acc[nt] = __builtin_amdgcn_mfma_f32_16x16x32_bf16(b1, afrag[1],
                                                              acc[nt], 0, 0, 0);
        }

        // ---- Scatter into swizzled bounce: row l15, granule g^ (row&7). ----
        // g = colw/4 + nt*4 + quad in [0,256). Conflicts: worst 2-way (free).
#pragma unroll
        for (int nt = 0; nt < 16; ++nt) {
            const int g = (wv << 6) + (nt << 2) + quad;
            *reinterpret_cast<f32x4*>(&bounce[(l15 << 10) + ((g ^ x) << 2)]) =
                acc[nt];
        }
        __syncthreads();

        // ---- Store: wave wv streams rows 4*wv..4*wv+3, 1 KB per instr,
        //      4 KB contiguous per row per chunk; chunks continue the row. ----
#pragma unroll
        for (int j = 0; j < 16; ++j) {
            const int rr = (wv << 2) + (j >> 2);
            const int g = ((j & 3) << 6) + lane;       // granule 0..255
            const f32x4 v = *reinterpret_cast<const f32x4*>(
                &bounce[(rr << 10) + ((g ^ (rr & 7)) << 2)]);
            *reinterpret_cast<f32x4*>(
                &C[(size_t)((bid << 4) + rr) * NDIM + (ch << 10) + (g << 2)]) = v;
        }
        __syncthreads();  // all reads done before next chunk's scatter
    }
}

// ---------------------------------------------------------------------------
// Fallback (ws too small): round-1 single-kernel version (known-correct).
// ---------------------------------------------------------------------------
#define LDS_STRIDE 72
__global__ __launch_bounds__(256, 3)
void tmatmul_fallback(const float* __restrict__ A, const float* __restrict__ B,
                      float* __restrict__ C) {
    __shared__ __align__(16) unsigned short smem[2 * 128 * LDS_STRIDE];
    unsigned short* sA = smem;
    unsigned short* sB = smem + 128 * LDS_STRIDE;

    const int tid = threadIdx.x;
    const int m0 = blockIdx.y << 7;
    const int n0 = blockIdx.x << 7;
    {
        const int row_base = tid >> 4;
        const int col = (tid & 15) << 2;
#pragma unroll
        for (int i = 0; i < 8; ++i) {
            const int row = row_base + (i << 4);
            const float4 v =
                *reinterpret_cast<const float4*>(&A[(size_t)(m0 + row) * KDIM + col]);
            ushort4 h;
            h.x = f32_to_bf16(v.x);
            h.y = f32_to_bf16(v.y);
            h.z = f32_to_bf16(v.z);
            h.w = f32_to_bf16(v.w);
            *reinterpret_cast<ushort4*>(&sA[row * LDS_STRIDE + col]) = h;
        }
    }
    {
#pragma unroll
        for (int i = 0; i < 8; ++i) {
            const int n = (tid & 63) + ((i & 1) << 6);
            const int k0 = ((tid >> 6) << 2) + ((i >> 1) << 4);
            const size_t gb = (size_t)k0 * NDIM + n0 + n;
            ushort4 h;
            h.x = f32_to_bf16(B[gb]);
            h.y = f32_to_bf16(B[gb + NDIM]);
            h.z = f32_to_bf16(B[gb + 2 * NDIM]);
            h.w = f32_to_bf16(B[gb + 3 * NDIM]);
            *reinterpret_cast<ushort4*>(&sB[n * LDS_STRIDE + k0]) = h;
        }
    }
    __syncthreads();

    const int lane = tid & 63;
    const int wv = tid >> 6;
    const int wm = (wv >> 1) << 6;
    const int wn = (wv & 1) << 6;
    const int l15 = lane & 15;
    const int quad = lane >> 4;

    bf16x8 afrag[4][2];
#pragma unroll
    for (int mt = 0; mt < 4; ++mt)
#pragma unroll
        for (int ks = 0; ks < 2; ++ks)
            afrag[mt][ks] = *reinterpret_cast<const bf16x8*>(
                &sA[(wm + mt * 16 + l15) * LDS_STRIDE + ks * 32 + quad * 8]);

    f32x4 acc[4][4];
    const f32x4 zero = {0.0f, 0.0f, 0.0f, 0.0f};
#pragma unroll
    for (int mt = 0; mt < 4; ++mt)
#pragma unroll
        for (int nt = 0; nt < 4; ++nt)
            acc[mt][nt] = zero;

#pragma unroll
    for (int nt = 0; nt < 4; ++nt) {
        const bf16x8 bf0 = *reinterpret_cast<const bf16x8*>(
            &sB[(wn + nt * 16 + l15) * LDS_STRIDE + quad * 8]);
        const bf16x8 bf1 = *reinterpret_cast<const bf16x8*>(
            &sB[(wn + nt * 16 + l15) * LDS_STRIDE + 32 + quad * 8]);
#pragma unroll
        for (int mt = 0; mt < 4; ++mt) {
            acc[mt][nt] = __builtin_amdgcn_mfma_f32_16x16x32_bf16(
                bf0, afrag[mt][0], acc[mt][nt], 0, 0, 0);
            acc[mt][nt] = __builtin_amdgcn_mfma_f32_16x16x32_bf16(
                bf1, afrag[mt][1], acc[mt][nt], 0, 0, 0);
        }
    }

    __syncthreads();

    float* cw = reinterpret_cast<float*>(smem) + (wv << 11);
#pragma unroll
    for (int mt = 0; mt < 4; ++mt) {
        float* buf = cw + ((mt & 1) << 10);
#pragma unroll
        for (int nt = 0; nt < 4; ++nt) {
            const int g = (nt << 2) + quad;
            *reinterpret_cast<f32x4*>(&buf[(l15 << 6) + ((g ^ l15) << 2)]) =
                acc[mt][nt];
        }
        const int m_base = m0 + wm + (mt << 4);
        const int n_base = n0 + wn + (l15 << 2);
#pragma unroll
        for (int j = 0; j < 4; ++j) {
            const int rr = (j << 2) + quad;
            const f32x4 v = *reinterpret_cast<const f32x4*>(
                &buf[(rr << 6) + ((l15 ^ rr) << 2)]);
            __builtin_nontemporal_store(
                v, reinterpret_cast<f32x4*>(&C[(size_t)(m_base + rr) * NDIM + n_base]));
        }
    }
}

extern "C" void kernel_launch(void* const* d_in, const int* in_sizes, int n_in,
                              void* d_out, int out_size, void* d_ws, size_t ws_size,
                              hipStream_t stream) {
    const float* A = (const float*)d_in[0];
    const float* B = (const float*)d_in[1];
    float* C = (float*)d_out;
    const size_t ws_needed = (size_t)128 * 8192 * sizeof(unsigned short);  // 2 MB
    if (d_ws != nullptr && ws_size >= ws_needed) {
        prep_kernel<<<dim3(128, 1, 1), dim3(256, 1, 1), 0, stream>>>(
            A, B, (unsigned short*)d_ws);
        tmatmul_kernel<<<dim3(512, 1, 1), dim3(256, 1, 1), 0, stream>>>(
            (const unsigned short*)d_ws, C);
    } else {
        dim3 grid(NDIM / 128, MDIM / 128);
        tmatmul_fallback<<<grid, dim3(256, 1, 1), 0, stream>>>(A, B, C);
    }
}

// Round 5
// 270.508 us; speedup vs baseline: 1.0585x; 1.0585x over previous
//
#include <hip/hip_runtime.h>

#define MDIM 8192
#define NDIM 8192
#define KDIM 64

typedef __attribute__((ext_vector_type(8))) short bf16x8;
typedef __attribute__((ext_vector_type(4))) float f32x4;

// LDS row stride in ushorts: 64 payload + 8 pad => 144 B rows.
// 144 % 16 == 0 keeps ds_read_b128 16B-aligned; 144B = 36 banks breaks the
// power-of-2 row->bank aliasing (residual 2-way conflicts are free on gfx950).
#define LDS_STRIDE 72

__device__ __forceinline__ unsigned short f32_to_bf16(float f) {
    union { float f; unsigned int u; } v;
    v.f = f;
    unsigned int u = v.u;
    u += 0x7FFFu + ((u >> 16) & 1u);  // round-to-nearest-even
    return (unsigned short)(u >> 16);
}

__global__ __launch_bounds__(256, 3)
void tmatmul_kernel(const float* __restrict__ A, const float* __restrict__ B,
                    float* __restrict__ C) {
    __shared__ __align__(16) unsigned short smem[2 * 128 * LDS_STRIDE];
    unsigned short* sA = smem;                       // sA[m][k], bf16 bits
    unsigned short* sB = smem + 128 * LDS_STRIDE;    // sB[n][k] (B^T), bf16 bits

    // ---- XCD-chunked block swizzle (the ONE change vs R1). ----
    // Default round-robin puts consecutive blocks (adjacent n-tiles of one row
    // band) on different XCDs -> each XCD's L2 writes sparse 512 B strips all
    // over the 256 MB C. Remap so XCD k owns swz in [k*512,(k+1)*512): that is
    // row bands y = 8k..8k+7, a contiguous 32 MB slab of C per XCD ->
    // page-dense write-back streams (fill-kernel-shaped). 4096 % 8 == 0 so
    // this chunked form is bijective.
    const int bid0 = blockIdx.x;                     // 0..4095
    const int swz = (bid0 & 7) * 512 + (bid0 >> 3);
    const int bx = swz & 63;                         // n tile
    const int by = swz >> 6;                         // m tile

    const int tid = threadIdx.x;
    const int m0 = by << 7;
    const int n0 = bx << 7;

    // ---- Stage A tile: 128 x 64 fp32 -> bf16, row-major. float4 coalesced. ----
    {
        const int row_base = tid >> 4;         // 0..15
        const int col = (tid & 15) << 2;       // 0,4,...,60
#pragma unroll
        for (int i = 0; i < 8; ++i) {
            const int row = row_base + (i << 4);
            const float4 v =
                *reinterpret_cast<const float4*>(&A[(size_t)(m0 + row) * KDIM + col]);
            ushort4 h;
            h.x = f32_to_bf16(v.x);
            h.y = f32_to_bf16(v.y);
            h.z = f32_to_bf16(v.z);
            h.w = f32_to_bf16(v.w);
            *reinterpret_cast<ushort4*>(&sA[row * LDS_STRIDE + col]) = h;
        }
    }

    // ---- Stage B tile: 64 x 128 fp32, transposed into sB[n][k] as bf16. ----
    {
#pragma unroll
        for (int i = 0; i < 8; ++i) {
            const int n = (tid & 63) + ((i & 1) << 6);           // 0..127
            const int k0 = ((tid >> 6) << 2) + ((i >> 1) << 4);  // 0,4,...,60
            const size_t gb = (size_t)k0 * NDIM + n0 + n;
            const float b0 = B[gb];
            const float b1 = B[gb + NDIM];
            const float b2 = B[gb + 2 * NDIM];
            const float b3 = B[gb + 3 * NDIM];
            ushort4 h;
            h.x = f32_to_bf16(b0);
            h.y = f32_to_bf16(b1);
            h.z = f32_to_bf16(b2);
            h.w = f32_to_bf16(b3);
            *reinterpret_cast<ushort4*>(&sB[n * LDS_STRIDE + k0]) = h;
        }
    }

    __syncthreads();

    // ---- Compute: 4 waves in 2x2, each wave a 64x64 strip (4x4 MFMA tiles). ----
    const int lane = tid & 63;
    const int wv = tid >> 6;
    const int wm = (wv >> 1) << 6;  // 0 or 64
    const int wn = (wv & 1) << 6;   // 0 or 64
    const int l15 = lane & 15;
    const int quad = lane >> 4;

    bf16x8 afrag[4][2];
#pragma unroll
    for (int mt = 0; mt < 4; ++mt)
#pragma unroll
        for (int ks = 0; ks < 2; ++ks)
            afrag[mt][ks] = *reinterpret_cast<const bf16x8*>(
                &sA[(wm + mt * 16 + l15) * LDS_STRIDE + ks * 32 + quad * 8]);

    f32x4 acc[4][4];
    const f32x4 zero = {0.0f, 0.0f, 0.0f, 0.0f};
#pragma unroll
    for (int mt = 0; mt < 4; ++mt)
#pragma unroll
        for (int nt = 0; nt < 4; ++nt)
            acc[mt][nt] = zero;

    // Operand swap: D = (B^T-frag) x (A^T-frag) = C^T tile. Lane holds
    // C[m = l15][n = quad*4 + reg].
#pragma unroll
    for (int nt = 0; nt < 4; ++nt) {
        const bf16x8 bf0 = *reinterpret_cast<const bf16x8*>(
            &sB[(wn + nt * 16 + l15) * LDS_STRIDE + quad * 8]);
        const bf16x8 bf1 = *reinterpret_cast<const bf16x8*>(
            &sB[(wn + nt * 16 + l15) * LDS_STRIDE + 32 + quad * 8]);
#pragma unroll
        for (int mt = 0; mt < 4; ++mt) {
            acc[mt][nt] = __builtin_amdgcn_mfma_f32_16x16x32_bf16(
                bf0, afrag[mt][0], acc[mt][nt], 0, 0, 0);
            acc[mt][nt] = __builtin_amdgcn_mfma_f32_16x16x32_bf16(
                bf1, afrag[mt][1], acc[mt][nt], 0, 0, 0);
        }
    }

    // All waves must be done reading sA/sB before we recycle the LDS as the
    // C bounce buffer.
    __syncthreads();

    // ---- Epilogue: per-wave swizzled LDS bounce -> fully contiguous stores.
    // Each wave scatters one 16x64 mt-slice into its private 4 KB slab
    // (granule g at row r stored at g^r -> conflict-free b128), re-reads
    // row-major, stores 4 rows x 256 B contiguous per global_store_dwordx4
    // (full 128 B lines, 1 KiB/instruction).
    float* cw = reinterpret_cast<float*>(smem) + (wv << 11);  // 8 KB per wave
#pragma unroll
    for (int mt = 0; mt < 4; ++mt) {
        float* buf = cw + ((mt & 1) << 10);  // ping-pong 4 KB halves
#pragma unroll
        for (int nt = 0; nt < 4; ++nt) {
            const int g = (nt << 2) + quad;
            *reinterpret_cast<f32x4*>(&buf[(l15 << 6) + ((g ^ l15) << 2)]) =
                acc[mt][nt];
        }
        const int m_base = m0 + wm + (mt << 4);
        const int n_base = n0 + wn + (l15 << 2);
#pragma unroll
        for (int j = 0; j < 4; ++j) {
            const int rr = (j << 2) + quad;
            const f32x4 v = *reinterpret_cast<const f32x4*>(
                &buf[(rr << 6) + ((l15 ^ rr) << 2)]);
            __builtin_nontemporal_store(
                v, reinterpret_cast<f32x4*>(&C[(size_t)(m_base + rr) * NDIM + n_base]));
        }
    }
}

extern "C" void kernel_launch(void* const* d_in, const int* in_sizes, int n_in,
                              void* d_out, int out_size, void* d_ws, size_t ws_size,
                              hipStream_t stream) {
    const float* A = (const float*)d_in[0];
    const float* B = (const float*)d_in[1];
    float* C = (float*)d_out;
    // 1-D grid so the kernel-side XCD swizzle fully controls tile placement.
    tmatmul_kernel<<<dim3((MDIM / 128) * (NDIM / 128), 1, 1), dim3(256, 1, 1), 0,
                    stream>>>(A, B, C);
}

// Round 6
// 258.692 us; speedup vs baseline: 1.1069x; 1.0457x over previous
//
#include <hip/hip_runtime.h>

#define MDIM 8192
#define NDIM 8192
#define KDIM 64

typedef __attribute__((ext_vector_type(8))) short bf16x8;
typedef __attribute__((ext_vector_type(4))) float f32x4;

// LDS row stride in ushorts: 64 payload + 8 pad => 144 B rows.
// 144 % 16 == 0 keeps ds_read_b128 16B-aligned; 144B = 36 banks breaks the
// power-of-2 row->bank aliasing (residual 2-way conflicts are free on gfx950).
#define LDS_STRIDE 72

__device__ __forceinline__ unsigned short f32_to_bf16(float f) {
    union { float f; unsigned int u; } v;
    v.f = f;
    unsigned int u = v.u;
    u += 0x7FFFu + ((u >> 16) & 1u);  // round-to-nearest-even
    return (unsigned short)(u >> 16);
}

__global__ __launch_bounds__(256, 3)
void tmatmul_kernel(const float* __restrict__ A, const float* __restrict__ B,
                    float* __restrict__ C) {
    __shared__ __align__(16) unsigned short smem[2 * 128 * LDS_STRIDE];
    unsigned short* sA = smem;                       // sA[m][k], bf16 bits
    unsigned short* sB = smem + 128 * LDS_STRIDE;    // sB[n][k] (B^T), bf16 bits

    const int tid = threadIdx.x;
    const int m0 = blockIdx.y << 7;
    const int n0 = blockIdx.x << 7;

    // ---- Stage A tile: 128 x 64 fp32 -> bf16, row-major. float4 coalesced. ----
    {
        const int row_base = tid >> 4;         // 0..15
        const int col = (tid & 15) << 2;       // 0,4,...,60
#pragma unroll
        for (int i = 0; i < 8; ++i) {
            const int row = row_base + (i << 4);
            const float4 v =
                *reinterpret_cast<const float4*>(&A[(size_t)(m0 + row) * KDIM + col]);
            ushort4 h;
            h.x = f32_to_bf16(v.x);
            h.y = f32_to_bf16(v.y);
            h.z = f32_to_bf16(v.z);
            h.w = f32_to_bf16(v.w);
            *reinterpret_cast<ushort4*>(&sA[row * LDS_STRIDE + col]) = h;
        }
    }

    // ---- Stage B tile: 64 x 128 fp32, transposed into sB[n][k] as bf16. ----
    {
#pragma unroll
        for (int i = 0; i < 8; ++i) {
            const int n = (tid & 63) + ((i & 1) << 6);           // 0..127
            const int k0 = ((tid >> 6) << 2) + ((i >> 1) << 4);  // 0,4,...,60
            const size_t gb = (size_t)k0 * NDIM + n0 + n;
            const float b0 = B[gb];
            const float b1 = B[gb + NDIM];
            const float b2 = B[gb + 2 * NDIM];
            const float b3 = B[gb + 3 * NDIM];
            ushort4 h;
            h.x = f32_to_bf16(b0);
            h.y = f32_to_bf16(b1);
            h.z = f32_to_bf16(b2);
            h.w = f32_to_bf16(b3);
            *reinterpret_cast<ushort4*>(&sB[n * LDS_STRIDE + k0]) = h;
        }
    }

    __syncthreads();

    // ---- Compute: 4 waves in 2x2, each wave a 64x64 strip (4x4 MFMA tiles). ----
    const int lane = tid & 63;
    const int wv = tid >> 6;
    const int wm = (wv >> 1) << 6;  // 0 or 64
    const int wn = (wv & 1) << 6;   // 0 or 64
    const int l15 = lane & 15;
    const int quad = lane >> 4;

    bf16x8 afrag[4][2];
#pragma unroll
    for (int mt = 0; mt < 4; ++mt)
#pragma unroll
        for (int ks = 0; ks < 2; ++ks)
            afrag[mt][ks] = *reinterpret_cast<const bf16x8*>(
                &sA[(wm + mt * 16 + l15) * LDS_STRIDE + ks * 32 + quad * 8]);

    f32x4 acc[4][4];
    const f32x4 zero = {0.0f, 0.0f, 0.0f, 0.0f};
#pragma unroll
    for (int mt = 0; mt < 4; ++mt)
#pragma unroll
        for (int nt = 0; nt < 4; ++nt)
            acc[mt][nt] = zero;

    // Operand swap: D = (B^T-frag) x (A^T-frag) = C^T tile. Lane holds
    // C[m = l15][n = quad*4 + reg].
#pragma unroll
    for (int nt = 0; nt < 4; ++nt) {
        const bf16x8 bf0 = *reinterpret_cast<const bf16x8*>(
            &sB[(wn + nt * 16 + l15) * LDS_STRIDE + quad * 8]);
        const bf16x8 bf1 = *reinterpret_cast<const bf16x8*>(
            &sB[(wn + nt * 16 + l15) * LDS_STRIDE + 32 + quad * 8]);
#pragma unroll
        for (int mt = 0; mt < 4; ++mt) {
            acc[mt][nt] = __builtin_amdgcn_mfma_f32_16x16x32_bf16(
                bf0, afrag[mt][0], acc[mt][nt], 0, 0, 0);
            acc[mt][nt] = __builtin_amdgcn_mfma_f32_16x16x32_bf16(
                bf1, afrag[mt][1], acc[mt][nt], 0, 0, 0);
        }
    }

    // All waves must be done reading sA/sB before we recycle the LDS as the
    // C bounce buffer.
    __syncthreads();

    // ---- Epilogue: per-wave swizzled LDS bounce -> fully contiguous stores.
    // Each wave scatters one 16x64 mt-slice into its private 4 KB slab
    // (granule g at row r stored at g^r -> conflict-free b128), re-reads
    // row-major, stores 4 rows x 256 B contiguous per global_store_dwordx4
    // (full 128 B lines, 1 KiB/instruction).
    //
    // A/B vs R1: PLAIN stores, not nontemporal. Theory: plain stores leave C
    // lines dirty in L2; the L2 writeback engine drains them lazily and
    // address-sorted, presenting page-dense streams to the HBM controllers
    // (how the 6.4 TB/s fill behaves). nt (evict-first) pushes lines out in
    // issue order = temporally scattered 256 B segments across 256 MB,
    // defeating that coalescing. Nothing in L2 needs protecting (A/B panels
    // are 4 MB and LLC-resident), so nt buys nothing.
    float* cw = reinterpret_cast<float*>(smem) + (wv << 11);  // 8 KB per wave
#pragma unroll
    for (int mt = 0; mt < 4; ++mt) {
        float* buf = cw + ((mt & 1) << 10);  // ping-pong 4 KB halves
#pragma unroll
        for (int nt = 0; nt < 4; ++nt) {
            const int g = (nt << 2) + quad;
            *reinterpret_cast<f32x4*>(&buf[(l15 << 6) + ((g ^ l15) << 2)]) =
                acc[mt][nt];
        }
        const int m_base = m0 + wm + (mt << 4);
        const int n_base = n0 + wn + (l15 << 2);
#pragma unroll
        for (int j = 0; j < 4; ++j) {
            const int rr = (j << 2) + quad;
            const f32x4 v = *reinterpret_cast<const f32x4*>(
                &buf[(rr << 6) + ((l15 ^ rr) << 2)]);
            *reinterpret_cast<f32x4*>(&C[(size_t)(m_base + rr) * NDIM + n_base]) = v;
        }
    }
}

extern "C" void kernel_launch(void* const* d_in, const int* in_sizes, int n_in,
                              void* d_out, int out_size, void* d_ws, size_t ws_size,
                              hipStream_t stream) {
    const float* A = (const float*)d_in[0];
    const float* B = (const float*)d_in[1];
    float* C = (float*)d_out;
    dim3 grid(NDIM / 128, MDIM / 128);
    tmatmul_kernel<<<grid, dim3(256, 1, 1), 0, stream>>>(A, B, C);
}